// Round 1
// baseline (221.143 us; speedup 1.0000x reference)
//
#include <hip/hip_runtime.h>
#include <hip/hip_bf16.h>
#include <stdint.h>

typedef unsigned short u16;
typedef __attribute__((ext_vector_type(4))) float f32x4;
typedef __attribute__((ext_vector_type(8))) short bf16x8;
typedef __attribute__((ext_vector_type(4))) unsigned int u32x4;
typedef __attribute__((ext_vector_type(2))) unsigned int u32x2;

#define DEV __device__ __forceinline__

// B=2, S=2048, DMODEL=1024, NHEAD=16, DK=64, scale = 1/8
static constexpr int S_ = 2048;

DEV u16 f2bf(float f) {
  union { float f; uint32_t u; } v; v.f = f;
  uint32_t u = v.u;
  return (u16)((u + 0x7fffu + ((u >> 16) & 1u)) >> 16);
}
DEV float bf2f(u16 h) {
  union { uint32_t u; float f; } v; v.u = ((uint32_t)h) << 16;
  return v.f;
}

DEV void gload_lds16(const u16* g, u16* l) {
  __builtin_amdgcn_global_load_lds(
      (const __attribute__((address_space(1))) void*)g,
      (__attribute__((address_space(3))) void*)l, 16, 0, 0);
}

// ---------------- prep: fp32 -> bf16 copies + transposed weights ----------------
// Qb/Kb/Vb: [4096][1024] bf16 of Q/K/V
// Wt[p][n][d] = W_p[h][d][k], n = h*64+k   (p = 0,1,2 for WQ,WK,WV)
// Wot[c][k]  = WO[k][c]
__global__ void prep_kernel(const float* __restrict__ Q, const float* __restrict__ K,
                            const float* __restrict__ V, const float* __restrict__ WQ,
                            const float* __restrict__ WK, const float* __restrict__ WV,
                            const float* __restrict__ WO,
                            u16* __restrict__ Qb, u16* __restrict__ Kb, u16* __restrict__ Vb,
                            u16* __restrict__ Wt, u16* __restrict__ Wot) {
  const int total = 16777216;
  int stride = gridDim.x * blockDim.x;
  for (int i = blockIdx.x * blockDim.x + threadIdx.x; i < total; i += stride) {
    if (i < 12582912) {
      int which = i >> 22; int j = i & 4194303;
      const float* src = which == 0 ? Q : (which == 1 ? K : V);
      u16* dst = which == 0 ? Qb : (which == 1 ? Kb : Vb);
      dst[j] = f2bf(src[j]);
    } else if (i < 15728640) {
      int j = i - 12582912;
      int p = j >> 20; int r = j & 1048575;
      int n = r >> 10, d = r & 1023;
      int h = n >> 6, k = n & 63;
      const float* src = p == 0 ? WQ : (p == 1 ? WK : WV);
      Wt[(size_t)p * 1048576 + r] = f2bf(src[(h * 1024 + d) * 64 + k]);
    } else {
      int j = i - 15728640;
      int c = j >> 10, k = j & 1023;
      Wot[j] = f2bf(WO[k * 1024 + c]);
    }
  }
}

// ---------------- GEMM: C[4096][1024] = A[4096][1024] * Bt[1024][1024]^T ----------------
// A row-major, Bt row n = output column n (k-contiguous). 128x128 tile, BK=64,
// 4 waves (2x2), global_load_lds staging with XOR chunk swizzle ch^(row&7).
template <int OUT_BF16>
__global__ __launch_bounds__(256, 2) void gemm_kernel(const u16* __restrict__ A,
                                                      const u16* __restrict__ Bt,
                                                      void* __restrict__ Cout) {
  __shared__ __align__(16) u16 Alds[128 * 64];
  __shared__ __align__(16) u16 Blds[128 * 64];
  const int tid = threadIdx.x;
  const int l = tid & 63, w = tid >> 6;
  const int wm = w >> 1, wn = w & 1;
  const int tileM = blockIdx.x * 128, tileN = blockIdx.y * 128;
  const int lr = l >> 3, lch = l & 7;

  f32x4 acc[4][4] = {};

  for (int kt = 0; kt < 16; ++kt) {
    const int k0 = kt * 64;
#pragma unroll
    for (int i = 0; i < 4; ++i) {
      int r = i * 32 + w * 8 + lr;
      int sch = lch ^ (r & 7);
      gload_lds16(A + (size_t)(tileM + r) * 1024 + k0 + sch * 8, Alds + i * 2048 + w * 512);
      gload_lds16(Bt + (size_t)(tileN + r) * 1024 + k0 + sch * 8, Blds + i * 2048 + w * 512);
    }
    __syncthreads();
    bf16x8 af[4][2], bfr[4][2];
#pragma unroll
    for (int m = 0; m < 4; ++m) {
#pragma unroll
      for (int kk = 0; kk < 2; ++kk) {
        int row = wm * 64 + m * 16 + (l & 15);
        int ch = ((l >> 4) + kk * 4) ^ (row & 7);
        af[m][kk] = *(const bf16x8*)(Alds + row * 64 + ch * 8);
        int rowb = wn * 64 + m * 16 + (l & 15);
        int chb = ((l >> 4) + kk * 4) ^ (rowb & 7);
        bfr[m][kk] = *(const bf16x8*)(Blds + rowb * 64 + chb * 8);
      }
    }
#pragma unroll
    for (int m = 0; m < 4; ++m)
#pragma unroll
      for (int n = 0; n < 4; ++n)
#pragma unroll
        for (int kk = 0; kk < 2; ++kk)
          acc[m][n] = __builtin_amdgcn_mfma_f32_16x16x32_bf16(af[m][kk], bfr[n][kk], acc[m][n], 0, 0, 0);
    __syncthreads();
  }
#pragma unroll
  for (int m = 0; m < 4; ++m) {
    int row0 = tileM + wm * 64 + m * 16 + ((l >> 4) << 2);
#pragma unroll
    for (int n = 0; n < 4; ++n) {
      int col = tileN + wn * 64 + n * 16 + (l & 15);
#pragma unroll
      for (int q = 0; q < 4; ++q) {
        if (OUT_BF16)
          ((u16*)Cout)[(size_t)(row0 + q) * 1024 + col] = f2bf(acc[m][n][q]);
        else
          ((float*)Cout)[(size_t)(row0 + q) * 1024 + col] = acc[m][n][q];
      }
    }
  }
}

// ---------------- transpose Vi[4096][1024] -> Vt[(bh*64+dk)][2048] ----------------
__global__ __launch_bounds__(256) void transposeV_kernel(const u16* __restrict__ Vi,
                                                         u16* __restrict__ Vt) {
  __shared__ __align__(16) u16 tl[64][72];
  const int tid = threadIdx.x;
  const int st = blockIdx.x * 64;
  const int bh = blockIdx.y;
  const int b = bh >> 4, h = bh & 15;
#pragma unroll
  for (int i = 0; i < 2; ++i) {
    int idx = i * 256 + tid;
    int s = idx >> 3, ch = idx & 7;
    const u16* src = Vi + (size_t)(b * 2048 + st + s) * 1024 + h * 64 + ch * 8;
    u32x2 a = *(const u32x2*)src;
    u32x2 bb = *(const u32x2*)(src + 4);
    *(u32x2*)&tl[s][ch * 8] = a;
    *(u32x2*)&tl[s][ch * 8 + 4] = bb;
  }
  __syncthreads();
#pragma unroll
  for (int i = 0; i < 2; ++i) {
    int idx = i * 256 + tid;
    int dk = idx >> 3, ch = idx & 7;
    u32x4 outv;
    u16* tp = (u16*)&outv;
#pragma unroll
    for (int j = 0; j < 8; ++j) tp[j] = tl[ch * 8 + j][dk];
    *(u32x4*)(Vt + ((size_t)bh * 64 + dk) * 2048 + st + ch * 8) = outv;
  }
}

// ---------------- flash attention ----------------
// grid (32 q-tiles, 32 bh), 256 threads = 4 waves; wave owns 16 q-rows.
// Qi/Ki: [b*2048+s][h*64+dk] bf16 ; Vt: [(bh*64+dk)][s] bf16 ; Hd: [bh*2048+s][dk] bf16
__global__ __launch_bounds__(256, 2) void attn_kernel(const u16* __restrict__ Qi,
                                                      const u16* __restrict__ Ki,
                                                      const u16* __restrict__ Vt,
                                                      u16* __restrict__ Hd) {
  __shared__ __align__(16) u16 Klds[64 * 64];
  __shared__ __align__(16) u16 Vtlds[64 * 64];
  __shared__ __align__(16) u16 Plds[4 * 16 * 72];
  const int tid = threadIdx.x;
  const int l = tid & 63, w = tid >> 6;
  const int qt = blockIdx.x * 64;
  const int bh = blockIdx.y;
  const int b = bh >> 4, h = bh & 15;
  const int lr = l >> 3, lch = l & 7;

  // Q fragments, pre-scaled by 1/sqrt(dk) = 0.125 (exact in bf16)
  bf16x8 qf[2];
  {
    int srow = qt + w * 16 + (l & 15);
    const u16* qp = Qi + (size_t)(b * 2048 + srow) * 1024 + h * 64 + ((l >> 4) * 8);
#pragma unroll
    for (int kk = 0; kk < 2; ++kk) {
      u32x4 t4 = *(const u32x4*)(qp + kk * 32);
      u16* tp = (u16*)&t4;
#pragma unroll
      for (int j = 0; j < 8; ++j) tp[j] = f2bf(bf2f(tp[j]) * 0.125f);
      qf[kk] = *(bf16x8*)&t4;
    }
  }

  f32x4 oacc[4] = {};
  float m_r[4], l_r[4];
#pragma unroll
  for (int q = 0; q < 4; ++q) { m_r[q] = -1e30f; l_r[q] = 0.f; }

  u16* Pw = Plds + w * (16 * 72);

  for (int kt = 0; kt < 32; ++kt) {
    // stage K tile [64 t][64 d] and V^T tile [64 dk][64 t], XOR-swizzled chunks
#pragma unroll
    for (int i = 0; i < 2; ++i) {
      int r = i * 32 + w * 8 + lr;
      int sch = lch ^ (r & 7);
      gload_lds16(Ki + (size_t)(b * 2048 + kt * 64 + r) * 1024 + h * 64 + sch * 8,
                  Klds + i * 2048 + w * 512);
      gload_lds16(Vt + ((size_t)bh * 64 + r) * 2048 + kt * 64 + sch * 8,
                  Vtlds + i * 2048 + w * 512);
    }
    __syncthreads();

    // S = Q K^T (scaled)
    f32x4 sacc[4] = {};
#pragma unroll
    for (int f = 0; f < 4; ++f) {
      int t = f * 16 + (l & 15);
#pragma unroll
      for (int kk = 0; kk < 2; ++kk) {
        int ch = ((l >> 4) + kk * 4) ^ (t & 7);
        bf16x8 kf = *(const bf16x8*)(Klds + t * 64 + ch * 8);
        sacc[f] = __builtin_amdgcn_mfma_f32_16x16x32_bf16(qf[kk], kf, sacc[f], 0, 0, 0);
      }
    }

    // online softmax (rows live in regs q, cols across lanes l&15)
    float cur[4];
#pragma unroll
    for (int q = 0; q < 4; ++q)
      cur[q] = fmaxf(fmaxf(sacc[0][q], sacc[1][q]), fmaxf(sacc[2][q], sacc[3][q]));
#pragma unroll
    for (int mask = 1; mask <= 8; mask <<= 1)
#pragma unroll
      for (int q = 0; q < 4; ++q) cur[q] = fmaxf(cur[q], __shfl_xor(cur[q], mask, 64));
    float al[4], rs[4];
#pragma unroll
    for (int q = 0; q < 4; ++q) {
      float mn = fmaxf(m_r[q], cur[q]);
      al[q] = __expf(m_r[q] - mn);
      m_r[q] = mn;
      rs[q] = 0.f;
    }
#pragma unroll
    for (int f = 0; f < 4; ++f)
#pragma unroll
      for (int q = 0; q < 4; ++q) {
        float p = __expf(sacc[f][q] - m_r[q]);
        rs[q] += p;
        Pw[((l >> 4) * 4 + q) * 72 + f * 16 + (l & 15)] = f2bf(p);
      }
#pragma unroll
    for (int mask = 1; mask <= 8; mask <<= 1)
#pragma unroll
      for (int q = 0; q < 4; ++q) rs[q] += __shfl_xor(rs[q], mask, 64);
#pragma unroll
    for (int q = 0; q < 4; ++q) l_r[q] = l_r[q] * al[q] + rs[q];
#pragma unroll
    for (int c = 0; c < 4; ++c)
#pragma unroll
      for (int q = 0; q < 4; ++q) oacc[c][q] *= al[q];

    // O += P V
#pragma unroll
    for (int c = 0; c < 4; ++c) {
      int cr = c * 16 + (l & 15);
#pragma unroll
      for (int th = 0; th < 2; ++th) {
        bf16x8 pf = *(const bf16x8*)(Pw + (l & 15) * 72 + (l >> 4) * 8 + th * 32);
        int ch = ((l >> 4) + 4 * th) ^ (cr & 7);
        bf16x8 vf = *(const bf16x8*)(Vtlds + cr * 64 + ch * 8);
        oacc[c] = __builtin_amdgcn_mfma_f32_16x16x32_bf16(pf, vf, oacc[c], 0, 0, 0);
      }
    }
    __syncthreads();
  }

  // epilogue: normalize, write headi in [B][H][S][DK] flat layout
#pragma unroll
  for (int c = 0; c < 4; ++c) {
    int dk = c * 16 + (l & 15);
#pragma unroll
    for (int q = 0; q < 4; ++q) {
      int srow = qt + w * 16 + (l >> 4) * 4 + q;
      Hd[((size_t)bh * 2048 + srow) * 64 + dk] = f2bf(oacc[c][q] / l_r[q]);
    }
  }
}

// ---------------- launch ----------------
extern "C" void kernel_launch(void* const* d_in, const int* in_sizes, int n_in,
                              void* d_out, int out_size, void* d_ws, size_t ws_size,
                              hipStream_t stream) {
  const float* Q = (const float*)d_in[0];
  const float* K = (const float*)d_in[1];
  const float* V = (const float*)d_in[2];
  const float* WQ = (const float*)d_in[3];
  const float* WK = (const float*)d_in[4];
  const float* WV = (const float*)d_in[5];
  const float* WO = (const float*)d_in[6];
  float* out = (float*)d_out;

  size_t off = 0;
  char* ws = (char*)d_ws;
  auto nxt = [&](size_t n) { void* p = ws + off; off += (n + 255) & ~(size_t)255; return p; };
  u16* Qb = (u16*)nxt(4096ull * 1024 * 2);
  u16* Kb = (u16*)nxt(4096ull * 1024 * 2);
  u16* Vb = (u16*)nxt(4096ull * 1024 * 2);
  u16* Qi = (u16*)nxt(4096ull * 1024 * 2);
  u16* Ki = (u16*)nxt(4096ull * 1024 * 2);
  u16* Vi = (u16*)nxt(4096ull * 1024 * 2);
  u16* Vtb = (u16*)nxt(4096ull * 1024 * 2);
  u16* Hd = (u16*)nxt(4096ull * 1024 * 2);
  u16* Wt = (u16*)nxt(3ull * 1048576 * 2);
  u16* Wot = (u16*)nxt(1048576ull * 2);

  prep_kernel<<<4096, 256, 0, stream>>>(Q, K, V, WQ, WK, WV, WO, Qb, Kb, Vb, Wt, Wot);

  dim3 gg(32, 8);
  gemm_kernel<1><<<gg, 256, 0, stream>>>(Qb, Wt, Qi);
  gemm_kernel<1><<<gg, 256, 0, stream>>>(Kb, Wt + 1048576, Ki);
  gemm_kernel<1><<<gg, 256, 0, stream>>>(Vb, Wt + 2 * 1048576, Vi);

  transposeV_kernel<<<dim3(32, 32), 256, 0, stream>>>(Vi, Vtb);

  attn_kernel<<<dim3(32, 32), 256, 0, stream>>>(Qi, Ki, Vtb, Hd);

  gemm_kernel<0><<<gg, 256, 0, stream>>>(Hd, Wot, out);
}

// Round 3
// 214.328 us; speedup vs baseline: 1.0318x; 1.0318x over previous
//
#include <hip/hip_runtime.h>
#include <hip/hip_bf16.h>
#include <stdint.h>

typedef unsigned short u16;
typedef unsigned int u32;
typedef __attribute__((ext_vector_type(4))) float f32x4;
typedef __attribute__((ext_vector_type(8))) short bf16x8;
typedef __attribute__((ext_vector_type(4))) unsigned int u32x4;
typedef __attribute__((ext_vector_type(2))) unsigned int u32x2;

#define DEV __device__ __forceinline__

DEV u16 f2bf(float f) {
  union { float f; uint32_t u; } v; v.f = f;
  uint32_t u = v.u;
  return (u16)((u + 0x7fffu + ((u >> 16) & 1u)) >> 16);
}
DEV float bf2f(u16 h) {
  union { uint32_t u; float f; } v; v.u = ((uint32_t)h) << 16;
  return v.f;
}

DEV void gload_lds16(const u16* g, u16* l) {
  __builtin_amdgcn_global_load_lds(
      (const __attribute__((address_space(1))) void*)g,
      (__attribute__((address_space(3))) void*)l, 16, 0, 0);
}

// ---------------- prep: fp32 -> bf16 + transposed weights ----------------
__global__ __launch_bounds__(256) void prep_kernel(
    const float* __restrict__ Q, const float* __restrict__ K, const float* __restrict__ V,
    const float* __restrict__ WQ, const float* __restrict__ WK, const float* __restrict__ WV,
    const float* __restrict__ WO,
    u16* __restrict__ Qb, u16* __restrict__ Kb, u16* __restrict__ Vb,
    u16* __restrict__ Wt, u16* __restrict__ Wot) {
  const int i = blockIdx.x * 256 + threadIdx.x;  // 1,048,576 threads
  // Q/K/V: 3 x 1,048,576 float4 -> bf16x4
#pragma unroll
  for (int it = 0; it < 3; ++it) {
    int idx = it * 1048576 + i;
    int which = idx >> 20, j = idx & 1048575;
    const float* src = which == 0 ? Q : (which == 1 ? K : V);
    u16* dst = which == 0 ? Qb : (which == 1 ? Kb : Vb);
    float4 v = ((const float4*)src)[j];
    u32x2 pk;
    pk[0] = (u32)f2bf(v.x) | ((u32)f2bf(v.y) << 16);
    pk[1] = (u32)f2bf(v.z) | ((u32)f2bf(v.w) << 16);
    *(u32x2*)(dst + (size_t)j * 4) = pk;
  }
  // weights: 4 scalar elements each
#pragma unroll
  for (int it = 0; it < 4; ++it) {
    int idx = it * 1048576 + i;
    if (idx < 3145728) {
      int p = idx >> 20, r = idx & 1048575;
      int n = r >> 10, d = r & 1023;
      int h = n >> 6, k = n & 63;
      const float* src = p == 0 ? WQ : (p == 1 ? WK : WV);
      Wt[idx] = f2bf(src[(h * 1024 + d) * 64 + k]);
    } else {
      int j = idx - 3145728;
      int c = j >> 10, k = j & 1023;
      Wot[j] = f2bf(WO[k * 1024 + c]);
    }
  }
}

// ---------------- GEMM: C[4096][1024] = A[4096][1024] * Bt^T, z-batched ----------------
template <int OUT_BF16>
__global__ __launch_bounds__(256, 2) void gemm_kernel(const u16* __restrict__ A,
                                                      const u16* __restrict__ Bt,
                                                      void* __restrict__ Cout) {
  __shared__ __align__(16) u16 Alds[128 * 64];
  __shared__ __align__(16) u16 Blds[128 * 64];
  const size_t zo = blockIdx.z;
  A += zo * 4194304;
  Bt += zo * 1048576;
  const int tid = threadIdx.x;
  const int l = tid & 63, w = tid >> 6;
  const int wm = w >> 1, wn = w & 1;
  const int tileM = blockIdx.x * 128, tileN = blockIdx.y * 128;
  const int lr = l >> 3, lch = l & 7;

  f32x4 acc[4][4] = {};

  for (int kt = 0; kt < 16; ++kt) {
    const int k0 = kt * 64;
#pragma unroll
    for (int i = 0; i < 4; ++i) {
      int r = i * 32 + w * 8 + lr;
      int sch = lch ^ (r & 7);
      gload_lds16(A + (size_t)(tileM + r) * 1024 + k0 + sch * 8, Alds + i * 2048 + w * 512);
      gload_lds16(Bt + (size_t)(tileN + r) * 1024 + k0 + sch * 8, Blds + i * 2048 + w * 512);
    }
    __syncthreads();
    bf16x8 af[4][2], bfr[4][2];
#pragma unroll
    for (int m = 0; m < 4; ++m) {
#pragma unroll
      for (int kk = 0; kk < 2; ++kk) {
        int row = wm * 64 + m * 16 + (l & 15);
        int ch = ((l >> 4) + kk * 4) ^ (row & 7);
        af[m][kk] = *(const bf16x8*)(Alds + row * 64 + ch * 8);
        int rowb = wn * 64 + m * 16 + (l & 15);
        int chb = ((l >> 4) + kk * 4) ^ (rowb & 7);
        bfr[m][kk] = *(const bf16x8*)(Blds + rowb * 64 + chb * 8);
      }
    }
#pragma unroll
    for (int m = 0; m < 4; ++m)
#pragma unroll
      for (int n = 0; n < 4; ++n)
#pragma unroll
        for (int kk = 0; kk < 2; ++kk)
          acc[m][n] = __builtin_amdgcn_mfma_f32_16x16x32_bf16(af[m][kk], bfr[n][kk], acc[m][n], 0, 0, 0);
    __syncthreads();
  }
#pragma unroll
  for (int m = 0; m < 4; ++m) {
    int row0 = tileM + wm * 64 + m * 16 + ((l >> 4) << 2);
#pragma unroll
    for (int n = 0; n < 4; ++n) {
      int col = tileN + wn * 64 + n * 16 + (l & 15);
#pragma unroll
      for (int q = 0; q < 4; ++q) {
        if (OUT_BF16)
          ((u16*)Cout)[zo * 4194304 + (size_t)(row0 + q) * 1024 + col] = f2bf(acc[m][n][q]);
        else
          ((float*)Cout)[(size_t)(row0 + q) * 1024 + col] = acc[m][n][q];
      }
    }
  }
}

// ---------------- transpose Vi[4096][1024] -> Vt[(bh*64+dk)][2048] ----------------
// (plain transpose, verified in round 1)
__global__ __launch_bounds__(256) void transposeV_kernel(const u16* __restrict__ Vi,
                                                         u16* __restrict__ Vt) {
  __shared__ __align__(16) u16 tl[64][72];
  const int tid = threadIdx.x;
  const int st = blockIdx.x * 64;
  const int bh = blockIdx.y;
  const int b = bh >> 4, h = bh & 15;
#pragma unroll
  for (int i = 0; i < 2; ++i) {
    int idx = i * 256 + tid;
    int s = idx >> 3, ch = idx & 7;
    const u16* src = Vi + (size_t)(b * 2048 + st + s) * 1024 + h * 64 + ch * 8;
    u32x2 a = *(const u32x2*)src;
    u32x2 bb = *(const u32x2*)(src + 4);
    *(u32x2*)&tl[s][ch * 8] = a;
    *(u32x2*)&tl[s][ch * 8 + 4] = bb;
  }
  __syncthreads();
#pragma unroll
  for (int i = 0; i < 2; ++i) {
    int idx = i * 256 + tid;
    int dk = idx >> 3, ch = idx & 7;
    u32x4 outv;
    u16* tp = (u16*)&outv;
#pragma unroll
    for (int j = 0; j < 8; ++j) tp[j] = tl[ch * 8 + j][dk];
    *(u32x4*)(Vt + ((size_t)bh * 64 + dk) * 2048 + st + ch * 8) = outv;
  }
}

// ---------------- flash attention ----------------
DEV void stage_kv(const u16* __restrict__ Ki, const u16* __restrict__ Vp,
                  u16* kl, u16* vl, int b, int bh, int h, int kt,
                  int w, int lr, int lch) {
#pragma unroll
  for (int i = 0; i < 2; ++i) {
    int r = i * 32 + w * 8 + lr;
    int sch = lch ^ (r & 7);
    gload_lds16(Ki + (size_t)(b * 2048 + kt * 64 + r) * 1024 + h * 64 + sch * 8,
                kl + i * 2048 + w * 512);
    gload_lds16(Vp + ((size_t)bh * 64 + r) * 2048 + kt * 64 + sch * 8,
                vl + i * 2048 + w * 512);
  }
}

__global__ __launch_bounds__(256, 3) void attn_kernel(const u16* __restrict__ Qi,
                                                      const u16* __restrict__ Ki,
                                                      const u16* __restrict__ Vp,
                                                      u16* __restrict__ Hd) {
  __shared__ __align__(16) u16 Klds[2][4096];
  __shared__ __align__(16) u16 Vlds[2][4096];
  __shared__ __align__(16) u16 Ptl[4][16 * 72];  // per-wave P [16 q][72 t-padded]
  const int tid = threadIdx.x;
  const int l = tid & 63, w = tid >> 6;
  const int g = l >> 4, x = l & 15;
  // bijective XCD chunk swizzle: dispatch d -> XCD d%8 gets contiguous 128-block chunk
  const int d = blockIdx.x + 32 * blockIdx.y;
  const int orig = (d & 7) * 128 + (d >> 3);
  const int qt = (orig & 31) * 64;
  const int bh = orig >> 5;
  const int b = bh >> 4, h = bh & 15;
  const int lr = l >> 3, lch = l & 7;
  u16* Pw = Ptl[w];

  // Q fragments pre-scaled by 1/sqrt(dk) = 0.125 (exact)
  bf16x8 qf[2];
  {
    int srow = qt + w * 16 + x;
    const u16* qp = Qi + (size_t)(b * 2048 + srow) * 1024 + h * 64 + g * 8;
#pragma unroll
    for (int kk = 0; kk < 2; ++kk) {
      u32x4 t4 = *(const u32x4*)(qp + kk * 32);
      u16* tp = (u16*)&t4;
#pragma unroll
      for (int j = 0; j < 8; ++j) tp[j] = f2bf(bf2f(tp[j]) * 0.125f);
      qf[kk] = *(bf16x8*)&t4;
    }
  }

  f32x4 oacc[4] = {};
  float m_r[4], l_r[4];
#pragma unroll
  for (int q = 0; q < 4; ++q) { m_r[q] = -1e30f; l_r[q] = 0.f; }

  stage_kv(Ki, Vp, Klds[0], Vlds[0], b, bh, h, 0, w, lr, lch);

  for (int kt = 0; kt < 32; ++kt) {
    const int cur = kt & 1;
    __syncthreads();  // compiler drains vmcnt(0)+lgkmcnt(0): staged tile `cur` ready
    if (kt + 1 < 32)
      stage_kv(Ki, Vp, Klds[cur ^ 1], Vlds[cur ^ 1], b, bh, h, kt + 1, w, lr, lch);
    const u16* kl = Klds[cur];
    const u16* vl = Vlds[cur];

    // S = Q K^T
    f32x4 sacc[4] = {};
    __builtin_amdgcn_s_setprio(1);
#pragma unroll
    for (int f = 0; f < 4; ++f) {
      int t = f * 16 + x;
#pragma unroll
      for (int kk = 0; kk < 2; ++kk) {
        int ch = (g + kk * 4) ^ (t & 7);
        bf16x8 kf = *(const bf16x8*)(kl + t * 64 + ch * 8);
        sacc[f] = __builtin_amdgcn_mfma_f32_16x16x32_bf16(qf[kk], kf, sacc[f], 0, 0, 0);
      }
    }
    __builtin_amdgcn_s_setprio(0);

    // online softmax: rows q = g*4+qreg, cols t = f*16+x
    float cur_m[4];
#pragma unroll
    for (int q = 0; q < 4; ++q)
      cur_m[q] = fmaxf(fmaxf(sacc[0][q], sacc[1][q]), fmaxf(sacc[2][q], sacc[3][q]));
#pragma unroll
    for (int mask = 1; mask <= 8; mask <<= 1)
#pragma unroll
      for (int q = 0; q < 4; ++q) cur_m[q] = fmaxf(cur_m[q], __shfl_xor(cur_m[q], mask, 64));

    float need = -1e30f;
#pragma unroll
    for (int q = 0; q < 4; ++q) need = fmaxf(need, cur_m[q] - m_r[q]);
    if (__any(need > 8.f)) {  // defer-rescale: skip when max growth small (P <= e^8)
#pragma unroll
      for (int q = 0; q < 4; ++q) {
        float mn = fmaxf(m_r[q], cur_m[q]);
        float al = __expf(m_r[q] - mn);
        m_r[q] = mn;
        l_r[q] *= al;
#pragma unroll
        for (int c = 0; c < 4; ++c) oacc[c][q] *= al;
      }
    }

    float rs[4] = {0.f, 0.f, 0.f, 0.f};
#pragma unroll
    for (int f = 0; f < 4; ++f)
#pragma unroll
      for (int q = 0; q < 4; ++q) {
        float p = __expf(sacc[f][q] - m_r[q]);
        rs[q] += p;
        Pw[(g * 4 + q) * 72 + f * 16 + x] = f2bf(p);
      }
#pragma unroll
    for (int mask = 1; mask <= 8; mask <<= 1)
#pragma unroll
      for (int q = 0; q < 4; ++q) rs[q] += __shfl_xor(rs[q], mask, 64);
#pragma unroll
    for (int q = 0; q < 4; ++q) l_r[q] += rs[q];

    // O += P V  (A-fragments read contiguous from padded P rows — verified layout)
    __builtin_amdgcn_s_setprio(1);
#pragma unroll
    for (int c = 0; c < 4; ++c) {
      int cr = c * 16 + x;
#pragma unroll
      for (int th = 0; th < 2; ++th) {
        bf16x8 pf = *(const bf16x8*)(Pw + x * 72 + g * 8 + th * 32);
        int ch = (g + 4 * th) ^ (cr & 7);
        bf16x8 vf = *(const bf16x8*)(vl + cr * 64 + ch * 8);
        oacc[c] = __builtin_amdgcn_mfma_f32_16x16x32_bf16(pf, vf, oacc[c], 0, 0, 0);
      }
    }
    __builtin_amdgcn_s_setprio(0);
  }

  // epilogue: normalize, write headi in [B][H][S][DK] flat layout
#pragma unroll
  for (int c = 0; c < 4; ++c) {
    int dk = c * 16 + x;
#pragma unroll
    for (int q = 0; q < 4; ++q) {
      int srow = qt + w * 16 + g * 4 + q;
      Hd[((size_t)bh * 2048 + srow) * 64 + dk] = f2bf(oacc[c][q] / l_r[q]);
    }
  }
}

// ---------------- launch ----------------
extern "C" void kernel_launch(void* const* d_in, const int* in_sizes, int n_in,
                              void* d_out, int out_size, void* d_ws, size_t ws_size,
                              hipStream_t stream) {
  const float* Q = (const float*)d_in[0];
  const float* K = (const float*)d_in[1];
  const float* V = (const float*)d_in[2];
  const float* WQ = (const float*)d_in[3];
  const float* WK = (const float*)d_in[4];
  const float* WV = (const float*)d_in[5];
  const float* WO = (const float*)d_in[6];
  float* out = (float*)d_out;

  size_t off = 0;
  char* ws = (char*)d_ws;
  auto nxt = [&](size_t n) { void* p = ws + off; off += (n + 255) & ~(size_t)255; return p; };
  u16* Qb = (u16*)nxt(3ull * 4096 * 1024 * 2);   // Qb,Kb,Vb contiguous
  u16* Qi = (u16*)nxt(3ull * 4096 * 1024 * 2);   // Qi,Ki,Vi contiguous
  u16* Vtb = (u16*)nxt(4096ull * 1024 * 2);
  u16* Hd = (u16*)nxt(4096ull * 1024 * 2);
  u16* Wt = (u16*)nxt(3ull * 1048576 * 2);
  u16* Wot = (u16*)nxt(1048576ull * 2);
  u16* Ki = Qi + 4194304;
  u16* Vi = Qi + 2 * 4194304;

  prep_kernel<<<4096, 256, 0, stream>>>(Q, K, V, WQ, WK, WV, WO, Qb, Qb + 4194304,
                                        Qb + 2 * 4194304, Wt, Wot);

  // fused Q/K/V projections: z picks (A, W, C) triple
  gemm_kernel<1><<<dim3(32, 8, 3), 256, 0, stream>>>(Qb, Wt, Qi);

  transposeV_kernel<<<dim3(32, 32), 256, 0, stream>>>(Vi, Vtb);

  attn_kernel<<<dim3(32, 32), 256, 0, stream>>>(Qi, Ki, Vtb, Hd);

  gemm_kernel<0><<<dim3(32, 8, 1), 256, 0, stream>>>(Hd, Wot, out);
}